// Round 1
// baseline (426.947 us; speedup 1.0000x reference)
//
#include <hip/hip_runtime.h>

namespace {

constexpr float SCALE = 0.35355339059327373f;  // (1/sqrt(2))^3

// x: (1024 rows, 65536)  ->  out: (1024 rows, 8 bands, 8192)
// Each thread: 4 consecutive output columns  => 32 consecutive input floats.
__global__ __launch_bounds__(256) void wpt3_kernel(const float* __restrict__ x,
                                                   float* __restrict__ out) {
    const long long g = (long long)blockIdx.x * 256 + threadIdx.x;  // group id
    const int row = (int)(g >> 11);   // 2048 groups of 4 cols per row
    const int kg  = (int)(g & 2047);

    const float4* in4 = reinterpret_cast<const float4*>(x + g * 32);
    float v[32];
    float4* v4 = reinterpret_cast<float4*>(v);
#pragma unroll
    for (int i = 0; i < 8; ++i) v4[i] = in4[i];

    float r[8][4];
#pragma unroll
    for (int j = 0; j < 4; ++j) {
        const float* p = v + 8 * j;
        const float s0 = p[0] + p[1], t0 = p[0] - p[1];
        const float s1 = p[2] + p[3], t1 = p[2] - p[3];
        const float s2 = p[4] + p[5], t2 = p[4] - p[5];
        const float s3 = p[6] + p[7], t3 = p[6] - p[7];
        const float ss0 = s0 + s1, st0 = s0 - s1, ss1 = s2 + s3, st1 = s2 - s3;
        const float ts0 = t0 + t1, tt0 = t0 - t1, ts1 = t2 + t3, tt1 = t2 - t3;
        // freq-ordered (Gray-code) bands: natural perm = [0,1,3,2,6,7,5,4]
        r[0][j] = (ss0 + ss1) * SCALE;  // n0 aaa
        r[1][j] = (ss0 - ss1) * SCALE;  // n1 aad
        r[2][j] = (st0 - st1) * SCALE;  // n3 add
        r[3][j] = (st0 + st1) * SCALE;  // n2 ada
        r[4][j] = (tt0 + tt1) * SCALE;  // n6 dda
        r[5][j] = (tt0 - tt1) * SCALE;  // n7 ddd
        r[6][j] = (ts0 - ts1) * SCALE;  // n5 dad
        r[7][j] = (ts0 + ts1) * SCALE;  // n4 daa
    }

    float* ob = out + (long long)row * 65536 + kg * 4;
#pragma unroll
    for (int i = 0; i < 8; ++i) {
        *reinterpret_cast<float4*>(ob + (long long)i * 8192) =
            make_float4(r[i][0], r[i][1], r[i][2], r[i][3]);
    }
}

}  // namespace

extern "C" void kernel_launch(void* const* d_in, const int* in_sizes, int n_in,
                              void* d_out, int out_size, void* d_ws, size_t ws_size,
                              hipStream_t stream) {
    const float* x = (const float*)d_in[0];
    float* out = (float*)d_out;
    // 64*16*65536 = 67,108,864 elements; 32 per thread -> 2,097,152 threads.
    const int total_groups = (64 * 16 * 65536) / 32;  // 2,097,152
    dim3 grid(total_groups / 256), block(256);
    hipLaunchKernelGGL(wpt3_kernel, grid, block, 0, stream, x, out);
}

// Round 2
// 414.127 us; speedup vs baseline: 1.0310x; 1.0310x over previous
//
#include <hip/hip_runtime.h>

namespace {

constexpr float SCALE = 0.35355339059327373f;  // (1/sqrt(2))^3

// x: (1024 rows, 65536) -> out: (1024 rows, 8 bands, 8192), Gray-code band order.
// Every 8 consecutive inputs produce one column in each of the 8 bands.
// Lane holds float4 = 2 level-1 pairs; level-2 lane-local; level-3 via
// __shfl_xor(1) with the neighbor lane (pair of lanes = one 8-group).
// Even lane writes "+" bands (slots 0,3,4,7), odd lane "-" bands (slot^1).
__global__ __launch_bounds__(256) void wpt3_kernel(const float* __restrict__ x,
                                                   float* __restrict__ out) {
    const long long tid = (long long)blockIdx.x * 256 + threadIdx.x;
    const int lane_odd = (int)(tid & 1);

    // Coalesced: lane-consecutive float4.
    const float4 v = *reinterpret_cast<const float4*>(x + tid * 4);

    // Level 1 (lane-local): 2 pairs.
    const float s0 = v.x + v.y, t0 = v.x - v.y;
    const float s1 = v.z + v.w, t1 = v.z - v.w;
    // Level 2 (lane-local): this lane holds half-group {aa,ad,da,dd}.
    const float p = s0 + s1;  // aa half
    const float q = s0 - s1;  // ad half
    const float r = t0 + t1;  // da half
    const float u = t0 - t1;  // dd half

    // Level 3: combine with neighbor lane (other half of the 8-group).
    const float pp = __shfl_xor(p, 1, 64);
    const float qq = __shfl_xor(q, 1, 64);
    const float rr = __shfl_xor(r, 1, 64);
    const float uu = __shfl_xor(u, 1, 64);

    // Even lane: own + recv (sum bands). Odd lane: recv - own (diff bands).
    const float b0 = (lane_odd ? (pp - p) : (p + pp)) * SCALE;  // slot 0 / 1: aaa / aad
    const float b1 = (lane_odd ? (qq - q) : (q + qq)) * SCALE;  // slot 3 / 2: ada / add
    const float b2 = (lane_odd ? (uu - u) : (u + uu)) * SCALE;  // slot 4 / 5: dda / ddd
    const float b3 = (lane_odd ? (rr - r) : (r + rr)) * SCALE;  // slot 7 / 6: daa / dad

    // Group index: pair of lanes -> one output column.
    const long long G = tid >> 1;
    const int row = (int)(G >> 13);       // 8192 columns per row
    const int col = (int)(G & 8191);
    float* ob = out + (long long)row * 65536 + col;

    ob[(long long)(0 ^ lane_odd) * 8192] = b0;
    ob[(long long)(3 ^ lane_odd) * 8192] = b1;
    ob[(long long)(4 ^ lane_odd) * 8192] = b2;
    ob[(long long)(7 ^ lane_odd) * 8192] = b3;
}

}  // namespace

extern "C" void kernel_launch(void* const* d_in, const int* in_sizes, int n_in,
                              void* d_out, int out_size, void* d_ws, size_t ws_size,
                              hipStream_t stream) {
    const float* x = (const float*)d_in[0];
    float* out = (float*)d_out;
    // 67,108,864 floats / 4 per thread = 16,777,216 threads.
    dim3 grid(65536), block(256);
    hipLaunchKernelGGL(wpt3_kernel, grid, block, 0, stream, x, out);
}